// Round 9
// baseline (667.170 us; speedup 1.0000x reference)
//
#include <hip/hip_runtime.h>
#include <hip/hip_bf16.h>
#include <float.h>
#include <math.h>

// Problem constants (B, L, H, D fixed by the reference setup)
constexpr int B = 4;
constexpr int L = 2048;
constexpr int H = 16;
constexpr int D = 64;
constexpr int U = 40;   // u_top = min(5*ceil(ln(2048)), 2048) = 40
constexpr int UG = 8;   // u's per flash block
constexpr int RCH = 8;  // key chunks of 256 rows (split-K)
constexpr int LPB = 16; // l's per block in compute_M

typedef float floatx4 __attribute__((ext_vector_type(4)));

// ---------------------------------------------------------------------------
// Kernel 0: out = v  (identity copy), nontemporal both ways.
// ---------------------------------------------------------------------------
__global__ __launch_bounds__(256) void copy_v_kernel(const float* __restrict__ v,
                                                     float* __restrict__ out, int n4) {
    int i = blockIdx.x * blockDim.x + threadIdx.x;
    int stride = gridDim.x * blockDim.x;
    const floatx4* src = reinterpret_cast<const floatx4*>(v);
    floatx4* dst = reinterpret_cast<floatx4*>(out);
    for (; i < n4; i += stride) {
        floatx4 x = __builtin_nontemporal_load(src + i);
        __builtin_nontemporal_store(x, dst + i);
    }
}

// ---------------------------------------------------------------------------
// Kernel 1 (round-4 proven, 83us): M[b,h,l], 16 l's per block, XCD-affinity
// by bh so each XCD's L2 holds 8 bh k-slices. 16-lane group per l.
// ---------------------------------------------------------------------------
template<int SKC>
__global__ __launch_bounds__(256) void compute_M_kernel2(const float* __restrict__ q,
                                                         const float* __restrict__ k,
                                                         const int* __restrict__ sidx,
                                                         float* __restrict__ M) {
    int blk = blockIdx.x;
    int xcd = blk & 7;
    int rest = blk >> 3;
    int bh_hi = rest & 7;
    int chunk = rest >> 3;            // 0 .. L/LPB-1
    int bh = bh_hi * 8 + xcd;         // bh%8 == blk%8
    int b = bh >> 4, h = bh & 15;

    int t = threadIdx.x;
    int lg = t >> 4;                  // local l 0..15
    int dg = t & 15;                  // 4-float group of D

    __shared__ int s_idx[LPB * SKC];
    for (int i = t; i < LPB * SKC; i += 256)
        s_idx[i] = sidx[(size_t)(chunk * LPB) * SKC + i];
    __syncthreads();

    int l = chunk * LPB + lg;
    floatx4 qv = __builtin_nontemporal_load(
        reinterpret_cast<const floatx4*>(q + ((size_t)(b * L + l) * H + h) * D + dg * 4));

    float mx = -FLT_MAX;
    float sm = 0.f;
    #pragma unroll 4
    for (int s = 0; s < SKC; ++s) {
        int kidx = s_idx[lg * SKC + s];
        floatx4 kv = *reinterpret_cast<const floatx4*>(
            k + ((size_t)(b * L + kidx) * H + h) * D + dg * 4);
        float p = qv.x * kv.x + qv.y * kv.y + qv.z * kv.z + qv.w * kv.w;
        #pragma unroll
        for (int off = 8; off >= 1; off >>= 1) p += __shfl_xor(p, off, 16);
        mx = fmaxf(mx, p);
        sm += p;
    }
    if (dg == 0) {
        M[(size_t)bh * L + l] = mx - sm * (1.0f / (float)L);
    }
}

// Fallback M for unexpected SK
__global__ __launch_bounds__(256) void compute_M_kernel(const float* __restrict__ q,
                                                        const float* __restrict__ k,
                                                        const int* __restrict__ sidx,
                                                        float* __restrict__ M, int SK) {
    int bl = blockIdx.x;
    int b = bl / L;
    int l = bl % L;
    int t = threadIdx.x;
    int h = t >> 4;
    int dg = t & 15;

    const float* qrow = q + ((size_t)(b * L + l)) * H * D + h * D + dg * 4;
    float4 qv = *reinterpret_cast<const float4*>(qrow);

    float mx = -FLT_MAX;
    float sm = 0.f;
    for (int s = 0; s < SK; ++s) {
        int kidx = sidx[l * SK + s];
        const float* krow = k + ((size_t)(b * L + kidx)) * H * D + h * D + dg * 4;
        float4 kv = *reinterpret_cast<const float4*>(krow);
        float p = qv.x * kv.x + qv.y * kv.y + qv.z * kv.z + qv.w * kv.w;
        #pragma unroll
        for (int off = 8; off >= 1; off >>= 1) p += __shfl_xor(p, off, 16);
        mx = fmaxf(mx, p);
        sm += p;
    }
    if (dg == 0) {
        M[((size_t)(b * H + h)) * L + l] = mx - sm * (1.0f / (float)L);
    }
}

// ---------------------------------------------------------------------------
// Kernel 2: one wave per (b,h), register-resident top-U, jax.lax.top_k
// tie-breaking (equal value -> lower index wins).
// ---------------------------------------------------------------------------
__global__ __launch_bounds__(64) void topk_wave_kernel(const float* __restrict__ M,
                                                       int* __restrict__ Mtop) {
    int bh = blockIdx.x;
    int lane = threadIdx.x;  // 0..63
    const float* m = M + (size_t)bh * L;

    float v[32];
    #pragma unroll
    for (int j = 0; j < 32; ++j) v[j] = m[j * 64 + lane];

    for (int u = 0; u < U; ++u) {
        float bv = -FLT_MAX;
        int bi = 0x7fffffff;
        #pragma unroll
        for (int j = 0; j < 32; ++j) {
            int idx = j * 64 + lane;
            bool take = (v[j] > bv) || (v[j] == bv && idx < bi);
            bv = take ? v[j] : bv;
            bi = take ? idx : bi;
        }
        #pragma unroll
        for (int off = 1; off < 64; off <<= 1) {
            float ov = __shfl_xor(bv, off);
            int   oi = __shfl_xor(bi, off);
            bool take = (ov > bv) || (ov == bv && oi < bi);
            bv = take ? ov : bv;
            bi = take ? oi : bi;
        }
        if (lane == 0) Mtop[bh * U + u] = bi;
        #pragma unroll
        for (int j = 0; j < 32; ++j) {
            if (bi == j * 64 + lane) v[j] = -FLT_MAX;
        }
    }
}

// ---------------------------------------------------------------------------
// Kernel 3: fused split-K flash attention for the selected queries.
// Block = (bh XCD-affine, u-group of 8, key-chunk of 256) = 2560 blocks.
// __launch_bounds__(256,4): cap 128 VGPRs so kr[16] (64 VGPR) stays in regs
// (without it hipcc assumes 1024-thread blocks -> 64-VGPR cap -> kr spills,
//  ~1.5 GB of scratch traffic; round-8 counters).
// ---------------------------------------------------------------------------
__global__ __launch_bounds__(256, 4) void flash_kernel(
        const float* __restrict__ q, const float* __restrict__ k,
        const float* __restrict__ v, const int* __restrict__ Mtop,
        float* __restrict__ pm, float* __restrict__ pl, float* __restrict__ pacc) {
    int blk = blockIdx.x;
    int xcd = blk & 7;
    int bh_hi = (blk >> 3) & 7;
    int rest = blk >> 6;            // 0..39
    int bh = bh_hi * 8 + xcd;       // bh%8 == blk%8 (XCD affinity)
    int ug = rest >> 3;             // 0..4
    int rch = rest & 7;             // 0..7
    int b = bh >> 4, h = bh & 15;
    int t = threadIdx.x;
    int w = t >> 6;

    __shared__ __align__(16) float qs[UG][D];   // 2 KB
    __shared__ float pe[UG][256];               // 8 KB
    __shared__ float redm[4][UG];
    __shared__ float redl[4][UG];
    __shared__ float racc[4][UG][64];           // 8 KB

    // stage 8 q rows (broadcast source)
    for (int i = t; i < UG * D; i += 256) {
        int u = i >> 6, dd = i & 63;
        int qi = Mtop[bh * U + ug * UG + u];
        qs[u][dd] = q[((size_t)(b * L + qi) * H + h) * D + dd];
    }
    __syncthreads();

    // scores: thread owns key row r
    int r = (rch << 8) + t;
    const float4* krow = reinterpret_cast<const float4*>(k + ((size_t)(b * L + r) * H + h) * D);
    float4 kr[16];
    #pragma unroll
    for (int j = 0; j < 16; ++j) kr[j] = krow[j];

    float s[UG];
    #pragma unroll
    for (int u = 0; u < UG; ++u) {
        const float4* qrow = reinterpret_cast<const float4*>(qs[u]);
        float a0 = 0.f, a1 = 0.f;
        #pragma unroll
        for (int j = 0; j < 16; j += 2) {
            float4 q0 = qrow[j];
            float4 q1 = qrow[j + 1];
            a0 += q0.x * kr[j].x + q0.y * kr[j].y + q0.z * kr[j].z + q0.w * kr[j].w;
            a1 += q1.x * kr[j+1].x + q1.y * kr[j+1].y + q1.z * kr[j+1].z + q1.w * kr[j+1].w;
        }
        s[u] = (a0 + a1) * 0.125f;  // 1/sqrt(64)
    }

    // block max per u
    #pragma unroll
    for (int u = 0; u < UG; ++u) {
        float m = s[u];
        #pragma unroll
        for (int off = 1; off < 64; off <<= 1) m = fmaxf(m, __shfl_xor(m, off));
        if ((t & 63) == 0) redm[w][u] = m;
    }
    __syncthreads();
    float m_u[UG];
    #pragma unroll
    for (int u = 0; u < UG; ++u)
        m_u[u] = fmaxf(fmaxf(redm[0][u], redm[1][u]), fmaxf(redm[2][u], redm[3][u]));

    // exp, block sum per u; stash e in LDS
    #pragma unroll
    for (int u = 0; u < UG; ++u) {
        float e = __expf(s[u] - m_u[u]);
        pe[u][t] = e;
        float ls = e;
        #pragma unroll
        for (int off = 1; off < 64; off <<= 1) ls += __shfl_xor(ls, off);
        if ((t & 63) == 0) redl[w][u] = ls;
    }
    __syncthreads();
    float l_u[UG];
    #pragma unroll
    for (int u = 0; u < UG; ++u)
        l_u[u] = redl[0][u] + redl[1][u] + redl[2][u] + redl[3][u];

    // PV partial: thread (w, d); wave w covers local rows w*64..+63
    int d = t & 63;
    const float* vb = v + ((size_t)b * L * H + h) * D + d;
    float acc[UG];
    #pragma unroll
    for (int u = 0; u < UG; ++u) acc[u] = 0.f;
    int rbase = (rch << 8) + (w << 6);
    for (int rr = 0; rr < 64; rr += 2) {
        float v1 = vb[(size_t)(rbase + rr) * H * D];
        float v2 = vb[(size_t)(rbase + rr + 1) * H * D];
        int rl = (w << 6) + rr;
        #pragma unroll
        for (int u = 0; u < UG; ++u) {
            acc[u] = fmaf(pe[u][rl + 1], v2, fmaf(pe[u][rl], v1, acc[u]));
        }
    }
    #pragma unroll
    for (int u = 0; u < UG; ++u) racc[w][u][d] = acc[u];
    __syncthreads();

    size_t pbase = (size_t)bh * U + ug * UG;
    for (int i = t; i < UG * 64; i += 256) {
        int u = i >> 6, dd = i & 63;
        float ssum = racc[0][u][dd] + racc[1][u][dd] + racc[2][u][dd] + racc[3][u][dd];
        pacc[((pbase + u) * RCH + rch) * 64 + dd] = ssum;
    }
    if (t == 0) {
        #pragma unroll
        for (int u = 0; u < UG; ++u) {
            pm[(pbase + u) * RCH + rch] = m_u[u];
            pl[(pbase + u) * RCH + rch] = l_u[u];
        }
    }
}

// ---------------------------------------------------------------------------
// Kernel 4: online-softmax merge of the RCH partials + scatter into out.
// Thread per (bh,u,d). Grid = B*H*U*64/256 = 640 blocks.
// ---------------------------------------------------------------------------
__global__ __launch_bounds__(256) void flash_merge_kernel(
        const float* __restrict__ pm, const float* __restrict__ pl,
        const float* __restrict__ pacc, const int* __restrict__ Mtop,
        float* __restrict__ out) {
    int idx = blockIdx.x * 256 + threadIdx.x;   // 0 .. B*H*U*64-1
    int dd = idx & 63;
    int bhu = idx >> 6;                          // 0..2559
    int bh = bhu / U;
    int b = bh / H, h = bh % H;

    float m = -FLT_MAX;
    #pragma unroll
    for (int c = 0; c < RCH; ++c) m = fmaxf(m, pm[bhu * RCH + c]);

    float Lsum = 0.f, acc = 0.f;
    #pragma unroll
    for (int c = 0; c < RCH; ++c) {
        float wgt = __expf(pm[bhu * RCH + c] - m);
        Lsum += pl[bhu * RCH + c] * wgt;
        acc  += pacc[((size_t)bhu * RCH + c) * 64 + dd] * wgt;
    }

    int qi = Mtop[bhu];
    out[((size_t)(b * L + qi) * H + h) * D + dd] = acc / Lsum;
}

// ---------------------------------------------------------------------------
// Fallback attention if workspace too small for the flash partials.
// ---------------------------------------------------------------------------
__global__ __launch_bounds__(256) void attn_kernel_fallback(
        const float* __restrict__ q, const float* __restrict__ k,
        const float* __restrict__ v, const int* __restrict__ Mtop,
        float* __restrict__ out) {
    int blk = blockIdx.x;
    int bh = blk / U;
    int u = blk % U;
    int b = bh / H;
    int h = bh % H;
    int qi = Mtop[bh * U + u];

    __shared__ float sc[L];
    __shared__ float qsf[D];
    __shared__ float red[4];
    __shared__ float ctx_s[4][D];

    int t = threadIdx.x;
    if (t < D) qsf[t] = q[((size_t)(b * L + qi)) * H * D + h * D + t];
    __syncthreads();

    float lm = -FLT_MAX;
    for (int i = t; i < L; i += 256) {
        const float* krow = k + ((size_t)(b * L + i)) * H * D + h * D;
        float acc = 0.f;
        #pragma unroll
        for (int dd = 0; dd < D; ++dd) acc += qsf[dd] * krow[dd];
        acc *= 0.125f;
        sc[i] = acc;
        lm = fmaxf(lm, acc);
    }
    #pragma unroll
    for (int off = 32; off >= 1; off >>= 1) lm = fmaxf(lm, __shfl_xor(lm, off));
    if ((t & 63) == 0) red[t >> 6] = lm;
    __syncthreads();
    float gm = fmaxf(fmaxf(red[0], red[1]), fmaxf(red[2], red[3]));

    float ls = 0.f;
    for (int i = t; i < L; i += 256) {
        float e = expf(sc[i] - gm);
        sc[i] = e;
        ls += e;
    }
    #pragma unroll
    for (int off = 32; off >= 1; off >>= 1) ls += __shfl_xor(ls, off);
    __syncthreads();
    if ((t & 63) == 0) red[t >> 6] = ls;
    __syncthreads();
    float inv = 1.0f / (red[0] + red[1] + red[2] + red[3]);

    int d = t & 63;
    int g = t >> 6;
    float acc = 0.f;
    for (int i = g; i < L; i += 4) {
        acc += sc[i] * v[((size_t)(b * L + i)) * H * D + h * D + d];
    }
    ctx_s[g][d] = acc;
    __syncthreads();
    if (g == 0) {
        float c = (ctx_s[0][d] + ctx_s[1][d] + ctx_s[2][d] + ctx_s[3][d]) * inv;
        out[((size_t)(b * L + qi)) * H * D + h * D + d] = c;
    }
}

// ---------------------------------------------------------------------------
extern "C" void kernel_launch(void* const* d_in, const int* in_sizes, int n_in,
                              void* d_out, int out_size, void* d_ws, size_t ws_size,
                              hipStream_t stream) {
    const float* q = (const float*)d_in[0];
    const float* k = (const float*)d_in[1];
    const float* v = (const float*)d_in[2];
    const int* sidx = (const int*)d_in[3];
    float* out = (float*)d_out;

    int SK = in_sizes[3] / L;  // sample_k (40 for this shape)

    // Workspace layout
    size_t offM = 0;                                            // B*H*L floats
    size_t offMtop = offM + (size_t)B * H * L * sizeof(float);
    size_t offPm = (offMtop + (size_t)B * H * U * sizeof(int) + 255) & ~(size_t)255;
    size_t offPl = offPm + (size_t)B * H * U * RCH * sizeof(float);
    size_t offPacc = (offPl + (size_t)B * H * U * RCH * sizeof(float) + 255) & ~(size_t)255;
    size_t needFlash = offPacc + (size_t)B * H * U * RCH * 64 * sizeof(float);

    float* M = (float*)((char*)d_ws + offM);
    int* Mtop = (int*)((char*)d_ws + offMtop);
    float* pm = (float*)((char*)d_ws + offPm);
    float* pl = (float*)((char*)d_ws + offPl);
    float* pacc = (float*)((char*)d_ws + offPacc);

    int n4 = (B * L * H * D) / 4;

    copy_v_kernel<<<2048, 256, 0, stream>>>(v, out, n4);

    if (SK == 40) {
        compute_M_kernel2<40><<<B * H * (L / LPB), 256, 0, stream>>>(q, k, sidx, M);
    } else {
        compute_M_kernel<<<B * L, 256, 0, stream>>>(q, k, sidx, M, SK);
    }
    topk_wave_kernel<<<B * H, 64, 0, stream>>>(M, Mtop);

    if (ws_size >= needFlash) {
        flash_kernel<<<B * H * (U / UG) * RCH, 256, 0, stream>>>(q, k, v, Mtop, pm, pl, pacc);
        flash_merge_kernel<<<B * H * U * 64 / 256, 256, 0, stream>>>(pm, pl, pacc, Mtop, out);
    } else {
        attn_kernel_fallback<<<B * H * U, 256, 0, stream>>>(q, k, v, Mtop, out);
    }
}

// Round 10
// 303.727 us; speedup vs baseline: 2.1966x; 2.1966x over previous
//
#include <hip/hip_runtime.h>
#include <hip/hip_bf16.h>
#include <float.h>
#include <math.h>

// Problem constants (B, L, H, D fixed by the reference setup)
constexpr int B = 4;
constexpr int L = 2048;
constexpr int H = 16;
constexpr int D = 64;
constexpr int U = 40;   // u_top = min(5*ceil(ln(2048)), 2048) = 40
constexpr int UG = 8;   // u's per flash block
constexpr int RCH = 8;  // key chunks of 256 rows (split-K)
constexpr int LPB = 16; // l's per block in compute_M

typedef float floatx4 __attribute__((ext_vector_type(4)));

// ---------------------------------------------------------------------------
// Kernel 0: out = v  (identity copy), nontemporal both ways.
// ---------------------------------------------------------------------------
__global__ __launch_bounds__(256) void copy_v_kernel(const float* __restrict__ v,
                                                     float* __restrict__ out, int n4) {
    int i = blockIdx.x * blockDim.x + threadIdx.x;
    int stride = gridDim.x * blockDim.x;
    const floatx4* src = reinterpret_cast<const floatx4*>(v);
    floatx4* dst = reinterpret_cast<floatx4*>(out);
    for (; i < n4; i += stride) {
        floatx4 x = __builtin_nontemporal_load(src + i);
        __builtin_nontemporal_store(x, dst + i);
    }
}

// ---------------------------------------------------------------------------
// Kernel 1 (round-4 proven, 83us): M[b,h,l], 16 l's per block, XCD-affinity
// by bh so each XCD's L2 holds 8 bh k-slices. 16-lane group per l.
// ---------------------------------------------------------------------------
template<int SKC>
__global__ __launch_bounds__(256) void compute_M_kernel2(const float* __restrict__ q,
                                                         const float* __restrict__ k,
                                                         const int* __restrict__ sidx,
                                                         float* __restrict__ M) {
    int blk = blockIdx.x;
    int xcd = blk & 7;
    int rest = blk >> 3;
    int bh_hi = rest & 7;
    int chunk = rest >> 3;            // 0 .. L/LPB-1
    int bh = bh_hi * 8 + xcd;         // bh%8 == blk%8
    int b = bh >> 4, h = bh & 15;

    int t = threadIdx.x;
    int lg = t >> 4;                  // local l 0..15
    int dg = t & 15;                  // 4-float group of D

    __shared__ int s_idx[LPB * SKC];
    for (int i = t; i < LPB * SKC; i += 256)
        s_idx[i] = sidx[(size_t)(chunk * LPB) * SKC + i];
    __syncthreads();

    int l = chunk * LPB + lg;
    floatx4 qv = __builtin_nontemporal_load(
        reinterpret_cast<const floatx4*>(q + ((size_t)(b * L + l) * H + h) * D + dg * 4));

    float mx = -FLT_MAX;
    float sm = 0.f;
    #pragma unroll 4
    for (int s = 0; s < SKC; ++s) {
        int kidx = s_idx[lg * SKC + s];
        floatx4 kv = *reinterpret_cast<const floatx4*>(
            k + ((size_t)(b * L + kidx) * H + h) * D + dg * 4);
        float p = qv.x * kv.x + qv.y * kv.y + qv.z * kv.z + qv.w * kv.w;
        #pragma unroll
        for (int off = 8; off >= 1; off >>= 1) p += __shfl_xor(p, off, 16);
        mx = fmaxf(mx, p);
        sm += p;
    }
    if (dg == 0) {
        M[(size_t)bh * L + l] = mx - sm * (1.0f / (float)L);
    }
}

// Fallback M for unexpected SK
__global__ __launch_bounds__(256) void compute_M_kernel(const float* __restrict__ q,
                                                        const float* __restrict__ k,
                                                        const int* __restrict__ sidx,
                                                        float* __restrict__ M, int SK) {
    int bl = blockIdx.x;
    int b = bl / L;
    int l = bl % L;
    int t = threadIdx.x;
    int h = t >> 4;
    int dg = t & 15;

    const float* qrow = q + ((size_t)(b * L + l)) * H * D + h * D + dg * 4;
    float4 qv = *reinterpret_cast<const float4*>(qrow);

    float mx = -FLT_MAX;
    float sm = 0.f;
    for (int s = 0; s < SK; ++s) {
        int kidx = sidx[l * SK + s];
        const float* krow = k + ((size_t)(b * L + kidx)) * H * D + h * D + dg * 4;
        float4 kv = *reinterpret_cast<const float4*>(krow);
        float p = qv.x * kv.x + qv.y * kv.y + qv.z * kv.z + qv.w * kv.w;
        #pragma unroll
        for (int off = 8; off >= 1; off >>= 1) p += __shfl_xor(p, off, 16);
        mx = fmaxf(mx, p);
        sm += p;
    }
    if (dg == 0) {
        M[((size_t)(b * H + h)) * L + l] = mx - sm * (1.0f / (float)L);
    }
}

// ---------------------------------------------------------------------------
// Kernel 2: one wave per (b,h), register-resident top-U, jax.lax.top_k
// tie-breaking (equal value -> lower index wins).
// ---------------------------------------------------------------------------
__global__ __launch_bounds__(64) void topk_wave_kernel(const float* __restrict__ M,
                                                       int* __restrict__ Mtop) {
    int bh = blockIdx.x;
    int lane = threadIdx.x;  // 0..63
    const float* m = M + (size_t)bh * L;

    float v[32];
    #pragma unroll
    for (int j = 0; j < 32; ++j) v[j] = m[j * 64 + lane];

    for (int u = 0; u < U; ++u) {
        float bv = -FLT_MAX;
        int bi = 0x7fffffff;
        #pragma unroll
        for (int j = 0; j < 32; ++j) {
            int idx = j * 64 + lane;
            bool take = (v[j] > bv) || (v[j] == bv && idx < bi);
            bv = take ? v[j] : bv;
            bi = take ? idx : bi;
        }
        #pragma unroll
        for (int off = 1; off < 64; off <<= 1) {
            float ov = __shfl_xor(bv, off);
            int   oi = __shfl_xor(bi, off);
            bool take = (ov > bv) || (ov == bv && oi < bi);
            bv = take ? ov : bv;
            bi = take ? oi : bi;
        }
        if (lane == 0) Mtop[bh * U + u] = bi;
        #pragma unroll
        for (int j = 0; j < 32; ++j) {
            if (bi == j * 64 + lane) v[j] = -FLT_MAX;
        }
    }
}

// ---------------------------------------------------------------------------
// Kernel 3: fused split-K flash attention for the selected queries.
// Block = (bh XCD-affine, u-group of 8, key-chunk of 256) = 2560 blocks.
// Score phase is j-OUTER streaming: each float4 chunk of the k row is loaded
// once into 4 VGPRs and immediately folded into all 8 s[u] accumulators
// (q chunks broadcast from LDS). No register arrays -> no scratch spill
// (rounds 8/9: kr[16] reg-array version spilled ~1.6KB/thread = 1GB traffic).
// ---------------------------------------------------------------------------
__global__ __launch_bounds__(256) void flash_kernel(
        const float* __restrict__ q, const float* __restrict__ k,
        const float* __restrict__ v, const int* __restrict__ Mtop,
        float* __restrict__ pm, float* __restrict__ pl, float* __restrict__ pacc) {
    int blk = blockIdx.x;
    int xcd = blk & 7;
    int bh_hi = (blk >> 3) & 7;
    int rest = blk >> 6;            // 0..39
    int bh = bh_hi * 8 + xcd;       // bh%8 == blk%8 (XCD affinity)
    int ug = rest >> 3;             // 0..4
    int rch = rest & 7;             // 0..7
    int b = bh >> 4, h = bh & 15;
    int t = threadIdx.x;
    int w = t >> 6;

    __shared__ __align__(16) float qs[UG][D];   // 2 KB
    __shared__ float pe[UG][256];               // 8 KB
    __shared__ float redm[4][UG];
    __shared__ float redl[4][UG];
    __shared__ float racc[4][UG][64];           // 8 KB

    // stage 8 q rows (broadcast source)
    for (int i = t; i < UG * D; i += 256) {
        int u = i >> 6, dd = i & 63;
        int qi = Mtop[bh * U + ug * UG + u];
        qs[u][dd] = q[((size_t)(b * L + qi) * H + h) * D + dd];
    }
    __syncthreads();

    // scores: thread owns key row r; stream k in float4 chunks (j outer)
    int r = (rch << 8) + t;
    const float4* krow = reinterpret_cast<const float4*>(k + ((size_t)(b * L + r) * H + h) * D);

    float s[UG];
    #pragma unroll
    for (int u = 0; u < UG; ++u) s[u] = 0.f;
    #pragma unroll
    for (int j = 0; j < 16; ++j) {
        float4 kj = krow[j];
        #pragma unroll
        for (int u = 0; u < UG; ++u) {
            float4 qj = reinterpret_cast<const float4*>(qs[u])[j];
            s[u] = fmaf(kj.x, qj.x, fmaf(kj.y, qj.y, fmaf(kj.z, qj.z, fmaf(kj.w, qj.w, s[u]))));
        }
    }
    #pragma unroll
    for (int u = 0; u < UG; ++u) s[u] *= 0.125f;   // 1/sqrt(64)

    // block max per u
    #pragma unroll
    for (int u = 0; u < UG; ++u) {
        float m = s[u];
        #pragma unroll
        for (int off = 1; off < 64; off <<= 1) m = fmaxf(m, __shfl_xor(m, off));
        if ((t & 63) == 0) redm[w][u] = m;
    }
    __syncthreads();
    float m_u[UG];
    #pragma unroll
    for (int u = 0; u < UG; ++u)
        m_u[u] = fmaxf(fmaxf(redm[0][u], redm[1][u]), fmaxf(redm[2][u], redm[3][u]));

    // exp, block sum per u; stash e in LDS
    #pragma unroll
    for (int u = 0; u < UG; ++u) {
        float e = __expf(s[u] - m_u[u]);
        pe[u][t] = e;
        float ls = e;
        #pragma unroll
        for (int off = 1; off < 64; off <<= 1) ls += __shfl_xor(ls, off);
        if ((t & 63) == 0) redl[w][u] = ls;
    }
    __syncthreads();
    float l_u[UG];
    #pragma unroll
    for (int u = 0; u < UG; ++u)
        l_u[u] = redl[0][u] + redl[1][u] + redl[2][u] + redl[3][u];

    // PV partial: thread (w, d); wave w covers local rows w*64..+63
    int d = t & 63;
    const float* vb = v + ((size_t)b * L * H + h) * D + d;
    float acc[UG];
    #pragma unroll
    for (int u = 0; u < UG; ++u) acc[u] = 0.f;
    int rbase = (rch << 8) + (w << 6);
    for (int rr = 0; rr < 64; rr += 2) {
        float v1 = vb[(size_t)(rbase + rr) * H * D];
        float v2 = vb[(size_t)(rbase + rr + 1) * H * D];
        int rl = (w << 6) + rr;
        #pragma unroll
        for (int u = 0; u < UG; ++u) {
            acc[u] = fmaf(pe[u][rl + 1], v2, fmaf(pe[u][rl], v1, acc[u]));
        }
    }
    #pragma unroll
    for (int u = 0; u < UG; ++u) racc[w][u][d] = acc[u];
    __syncthreads();

    size_t pbase = (size_t)bh * U + ug * UG;
    for (int i = t; i < UG * 64; i += 256) {
        int u = i >> 6, dd = i & 63;
        float ssum = racc[0][u][dd] + racc[1][u][dd] + racc[2][u][dd] + racc[3][u][dd];
        pacc[((pbase + u) * RCH + rch) * 64 + dd] = ssum;
    }
    if (t == 0) {
        #pragma unroll
        for (int u = 0; u < UG; ++u) {
            pm[(pbase + u) * RCH + rch] = m_u[u];
            pl[(pbase + u) * RCH + rch] = l_u[u];
        }
    }
}

// ---------------------------------------------------------------------------
// Kernel 4: online-softmax merge of the RCH partials + scatter into out.
// Thread per (bh,u,d). Grid = B*H*U*64/256 = 640 blocks.
// ---------------------------------------------------------------------------
__global__ __launch_bounds__(256) void flash_merge_kernel(
        const float* __restrict__ pm, const float* __restrict__ pl,
        const float* __restrict__ pacc, const int* __restrict__ Mtop,
        float* __restrict__ out) {
    int idx = blockIdx.x * 256 + threadIdx.x;   // 0 .. B*H*U*64-1
    int dd = idx & 63;
    int bhu = idx >> 6;                          // 0..2559
    int bh = bhu / U;
    int b = bh / H, h = bh % H;

    float m = -FLT_MAX;
    #pragma unroll
    for (int c = 0; c < RCH; ++c) m = fmaxf(m, pm[bhu * RCH + c]);

    float Lsum = 0.f, acc = 0.f;
    #pragma unroll
    for (int c = 0; c < RCH; ++c) {
        float wgt = __expf(pm[bhu * RCH + c] - m);
        Lsum += pl[bhu * RCH + c] * wgt;
        acc  += pacc[((size_t)bhu * RCH + c) * 64 + dd] * wgt;
    }

    int qi = Mtop[bhu];
    out[((size_t)(b * L + qi) * H + h) * D + dd] = acc / Lsum;
}

// ---------------------------------------------------------------------------
// Fallback attention if workspace too small for the flash partials.
// ---------------------------------------------------------------------------
__global__ __launch_bounds__(256) void attn_kernel_fallback(
        const float* __restrict__ q, const float* __restrict__ k,
        const float* __restrict__ v, const int* __restrict__ Mtop,
        float* __restrict__ out) {
    int blk = blockIdx.x;
    int bh = blk / U;
    int u = blk % U;
    int b = bh / H;
    int h = bh % H;
    int qi = Mtop[bh * U + u];

    __shared__ float sc[L];
    __shared__ float qsf[D];
    __shared__ float red[4];
    __shared__ float ctx_s[4][D];

    int t = threadIdx.x;
    if (t < D) qsf[t] = q[((size_t)(b * L + qi)) * H * D + h * D + t];
    __syncthreads();

    float lm = -FLT_MAX;
    for (int i = t; i < L; i += 256) {
        const float* krow = k + ((size_t)(b * L + i)) * H * D + h * D;
        float acc = 0.f;
        #pragma unroll
        for (int dd = 0; dd < D; ++dd) acc += qsf[dd] * krow[dd];
        acc *= 0.125f;
        sc[i] = acc;
        lm = fmaxf(lm, acc);
    }
    #pragma unroll
    for (int off = 32; off >= 1; off >>= 1) lm = fmaxf(lm, __shfl_xor(lm, off));
    if ((t & 63) == 0) red[t >> 6] = lm;
    __syncthreads();
    float gm = fmaxf(fmaxf(red[0], red[1]), fmaxf(red[2], red[3]));

    float ls = 0.f;
    for (int i = t; i < L; i += 256) {
        float e = expf(sc[i] - gm);
        sc[i] = e;
        ls += e;
    }
    #pragma unroll
    for (int off = 32; off >= 1; off >>= 1) ls += __shfl_xor(ls, off);
    __syncthreads();
    if ((t & 63) == 0) red[t >> 6] = ls;
    __syncthreads();
    float inv = 1.0f / (red[0] + red[1] + red[2] + red[3]);

    int d = t & 63;
    int g = t >> 6;
    float acc = 0.f;
    for (int i = g; i < L; i += 4) {
        acc += sc[i] * v[((size_t)(b * L + i)) * H * D + h * D + d];
    }
    ctx_s[g][d] = acc;
    __syncthreads();
    if (g == 0) {
        float c = (ctx_s[0][d] + ctx_s[1][d] + ctx_s[2][d] + ctx_s[3][d]) * inv;
        out[((size_t)(b * L + qi)) * H * D + h * D + d] = c;
    }
}

// ---------------------------------------------------------------------------
extern "C" void kernel_launch(void* const* d_in, const int* in_sizes, int n_in,
                              void* d_out, int out_size, void* d_ws, size_t ws_size,
                              hipStream_t stream) {
    const float* q = (const float*)d_in[0];
    const float* k = (const float*)d_in[1];
    const float* v = (const float*)d_in[2];
    const int* sidx = (const int*)d_in[3];
    float* out = (float*)d_out;

    int SK = in_sizes[3] / L;  // sample_k (40 for this shape)

    // Workspace layout
    size_t offM = 0;                                            // B*H*L floats
    size_t offMtop = offM + (size_t)B * H * L * sizeof(float);
    size_t offPm = (offMtop + (size_t)B * H * U * sizeof(int) + 255) & ~(size_t)255;
    size_t offPl = offPm + (size_t)B * H * U * RCH * sizeof(float);
    size_t offPacc = (offPl + (size_t)B * H * U * RCH * sizeof(float) + 255) & ~(size_t)255;
    size_t needFlash = offPacc + (size_t)B * H * U * RCH * 64 * sizeof(float);

    float* M = (float*)((char*)d_ws + offM);
    int* Mtop = (int*)((char*)d_ws + offMtop);
    float* pm = (float*)((char*)d_ws + offPm);
    float* pl = (float*)((char*)d_ws + offPl);
    float* pacc = (float*)((char*)d_ws + offPacc);

    int n4 = (B * L * H * D) / 4;

    copy_v_kernel<<<2048, 256, 0, stream>>>(v, out, n4);

    if (SK == 40) {
        compute_M_kernel2<40><<<B * H * (L / LPB), 256, 0, stream>>>(q, k, sidx, M);
    } else {
        compute_M_kernel<<<B * L, 256, 0, stream>>>(q, k, sidx, M, SK);
    }
    topk_wave_kernel<<<B * H, 64, 0, stream>>>(M, Mtop);

    if (ws_size >= needFlash) {
        flash_kernel<<<B * H * (U / UG) * RCH, 256, 0, stream>>>(q, k, v, Mtop, pm, pl, pacc);
        flash_merge_kernel<<<B * H * U * 64 / 256, 256, 0, stream>>>(pm, pl, pacc, Mtop, out);
    } else {
        attn_kernel_fallback<<<B * H * U, 256, 0, stream>>>(q, k, v, Mtop, out);
    }
}

// Round 11
// 229.624 us; speedup vs baseline: 2.9055x; 1.3227x over previous
//
#include <hip/hip_runtime.h>
#include <hip/hip_bf16.h>
#include <float.h>
#include <math.h>

// Problem constants (B, L, H, D fixed by the reference setup)
constexpr int B = 4;
constexpr int L = 2048;
constexpr int H = 16;
constexpr int D = 64;
constexpr int U = 40;   // u_top = min(5*ceil(ln(2048)), 2048) = 40
constexpr int RCH = 8;  // key chunks of 256 rows (split-K blocks)
constexpr int NCHK = RCH * 4;  // 32 partial chunks (per-wave)
constexpr int LPB = 16; // l's per block in compute_M

typedef float floatx4 __attribute__((ext_vector_type(4)));

// ---------------------------------------------------------------------------
// Kernel 0: out = v  (identity copy), nontemporal both ways.
// ---------------------------------------------------------------------------
__global__ __launch_bounds__(256) void copy_v_kernel(const float* __restrict__ v,
                                                     float* __restrict__ out, int n4) {
    int i = blockIdx.x * blockDim.x + threadIdx.x;
    int stride = gridDim.x * blockDim.x;
    const floatx4* src = reinterpret_cast<const floatx4*>(v);
    floatx4* dst = reinterpret_cast<floatx4*>(out);
    for (; i < n4; i += stride) {
        floatx4 x = __builtin_nontemporal_load(src + i);
        __builtin_nontemporal_store(x, dst + i);
    }
}

// ---------------------------------------------------------------------------
// Kernel 1 (round-4 proven, 83us): M[b,h,l], 16 l's per block, XCD-affinity
// by bh so each XCD's L2 holds 8 bh k-slices. 16-lane group per l.
// ---------------------------------------------------------------------------
template<int SKC>
__global__ __launch_bounds__(256) void compute_M_kernel2(const float* __restrict__ q,
                                                         const float* __restrict__ k,
                                                         const int* __restrict__ sidx,
                                                         float* __restrict__ M) {
    int blk = blockIdx.x;
    int xcd = blk & 7;
    int rest = blk >> 3;
    int bh_hi = rest & 7;
    int chunk = rest >> 3;            // 0 .. L/LPB-1
    int bh = bh_hi * 8 + xcd;         // bh%8 == blk%8
    int b = bh >> 4, h = bh & 15;

    int t = threadIdx.x;
    int lg = t >> 4;                  // local l 0..15
    int dg = t & 15;                  // 4-float group of D

    __shared__ int s_idx[LPB * SKC];
    for (int i = t; i < LPB * SKC; i += 256)
        s_idx[i] = sidx[(size_t)(chunk * LPB) * SKC + i];
    __syncthreads();

    int l = chunk * LPB + lg;
    floatx4 qv = __builtin_nontemporal_load(
        reinterpret_cast<const floatx4*>(q + ((size_t)(b * L + l) * H + h) * D + dg * 4));

    float mx = -FLT_MAX;
    float sm = 0.f;
    #pragma unroll 4
    for (int s = 0; s < SKC; ++s) {
        int kidx = s_idx[lg * SKC + s];
        floatx4 kv = *reinterpret_cast<const floatx4*>(
            k + ((size_t)(b * L + kidx) * H + h) * D + dg * 4);
        float p = qv.x * kv.x + qv.y * kv.y + qv.z * kv.z + qv.w * kv.w;
        #pragma unroll
        for (int off = 8; off >= 1; off >>= 1) p += __shfl_xor(p, off, 16);
        mx = fmaxf(mx, p);
        sm += p;
    }
    if (dg == 0) {
        M[(size_t)bh * L + l] = mx - sm * (1.0f / (float)L);
    }
}

// Fallback M for unexpected SK
__global__ __launch_bounds__(256) void compute_M_kernel(const float* __restrict__ q,
                                                        const float* __restrict__ k,
                                                        const int* __restrict__ sidx,
                                                        float* __restrict__ M, int SK) {
    int bl = blockIdx.x;
    int b = bl / L;
    int l = bl % L;
    int t = threadIdx.x;
    int h = t >> 4;
    int dg = t & 15;

    const float* qrow = q + ((size_t)(b * L + l)) * H * D + h * D + dg * 4;
    float4 qv = *reinterpret_cast<const float4*>(qrow);

    float mx = -FLT_MAX;
    float sm = 0.f;
    for (int s = 0; s < SK; ++s) {
        int kidx = sidx[l * SK + s];
        const float* krow = k + ((size_t)(b * L + kidx)) * H * D + h * D + dg * 4;
        float4 kv = *reinterpret_cast<const float4*>(krow);
        float p = qv.x * kv.x + qv.y * kv.y + qv.z * kv.z + qv.w * kv.w;
        #pragma unroll
        for (int off = 8; off >= 1; off >>= 1) p += __shfl_xor(p, off, 16);
        mx = fmaxf(mx, p);
        sm += p;
    }
    if (dg == 0) {
        M[((size_t)(b * H + h)) * L + l] = mx - sm * (1.0f / (float)L);
    }
}

// ---------------------------------------------------------------------------
// Kernel 2: one wave per (b,h), register-resident top-U, jax.lax.top_k
// tie-breaking (equal value -> lower index wins).
// ---------------------------------------------------------------------------
__global__ __launch_bounds__(64) void topk_wave_kernel(const float* __restrict__ M,
                                                       int* __restrict__ Mtop) {
    int bh = blockIdx.x;
    int lane = threadIdx.x;  // 0..63
    const float* m = M + (size_t)bh * L;

    float v[32];
    #pragma unroll
    for (int j = 0; j < 32; ++j) v[j] = m[j * 64 + lane];

    for (int u = 0; u < U; ++u) {
        float bv = -FLT_MAX;
        int bi = 0x7fffffff;
        #pragma unroll
        for (int j = 0; j < 32; ++j) {
            int idx = j * 64 + lane;
            bool take = (v[j] > bv) || (v[j] == bv && idx < bi);
            bv = take ? v[j] : bv;
            bi = take ? idx : bi;
        }
        #pragma unroll
        for (int off = 1; off < 64; off <<= 1) {
            float ov = __shfl_xor(bv, off);
            int   oi = __shfl_xor(bi, off);
            bool take = (ov > bv) || (ov == bv && oi < bi);
            bv = take ? ov : bv;
            bi = take ? oi : bi;
        }
        if (lane == 0) Mtop[bh * U + u] = bi;
        #pragma unroll
        for (int j = 0; j < 32; ++j) {
            if (bi == j * 64 + lane) v[j] = -FLT_MAX;
        }
    }
}

// ---------------------------------------------------------------------------
// Kernel 3: fused split-K flash attention, ALL 40 u's per block.
// Block = (bh XCD-affine, key-chunk of 256) = 512 blocks -> k and v are read
// exactly once each (round 10's 5 ug-blocks re-read them 5x). Statically
// indexed s[40]/acc[40]; pe read as wave-uniform float4 broadcasts. Per-wave
// PV partials go straight to pacc (32 chunks/(bh,u)) -- no LDS racc, no extra
// barriers; the merge kernel absorbs the 4x partial count.
// ---------------------------------------------------------------------------
__global__ __launch_bounds__(256) void flash_kernel(
        const float* __restrict__ q, const float* __restrict__ k,
        const float* __restrict__ v, const int* __restrict__ Mtop,
        float* __restrict__ pm, float* __restrict__ pl, float* __restrict__ pacc) {
    int blk = blockIdx.x;           // 0..511
    int xcd = blk & 7;
    int bh = ((blk >> 3) & 7) * 8 + xcd;   // bh%8 == blk%8 (XCD affinity)
    int rch = blk >> 6;             // 0..7
    int b = bh >> 4, h = bh & 15;
    int t = threadIdx.x;
    int w = t >> 6;

    __shared__ __align__(16) float qs[U][D];    // 10 KB
    __shared__ __align__(16) float pe[U][256];  // 40 KB
    __shared__ float redm[4][U];                // 640 B
    __shared__ float redl[4][U];                // 640 B

    // stage 40 q rows (broadcast source)
    for (int i = t; i < U * D; i += 256) {
        int u = i >> 6, dd = i & 63;
        int qi = Mtop[bh * U + u];
        qs[u][dd] = q[((size_t)(b * L + qi) * H + h) * D + dd];
    }
    __syncthreads();

    // scores: thread owns key row r; stream k in float4 chunks (j outer)
    int r = (rch << 8) + t;
    const float4* krow = reinterpret_cast<const float4*>(k + ((size_t)(b * L + r) * H + h) * D);

    float s[U];
    #pragma unroll
    for (int u = 0; u < U; ++u) s[u] = 0.f;
    #pragma unroll 2
    for (int j = 0; j < 16; ++j) {
        float4 kj = krow[j];
        #pragma unroll
        for (int u = 0; u < U; ++u) {
            float4 qj = reinterpret_cast<const float4*>(qs[u])[j];
            s[u] = fmaf(kj.x, qj.x, fmaf(kj.y, qj.y, fmaf(kj.z, qj.z, fmaf(kj.w, qj.w, s[u]))));
        }
    }

    // block max per u (shfl across wave, then LDS across 4 waves)
    #pragma unroll
    for (int u = 0; u < U; ++u) {
        float m = s[u] * 0.125f;    // 1/sqrt(64)
        s[u] = m;
        #pragma unroll
        for (int off = 1; off < 64; off <<= 1) m = fmaxf(m, __shfl_xor(m, off));
        if ((t & 63) == 0) redm[w][u] = m;
    }
    __syncthreads();

    // exp + block sum per u; stash e in LDS
    #pragma unroll
    for (int u = 0; u < U; ++u) {
        float m_u = fmaxf(fmaxf(redm[0][u], redm[1][u]), fmaxf(redm[2][u], redm[3][u]));
        float e = __expf(s[u] - m_u);
        pe[u][t] = e;
        float ls = e;
        #pragma unroll
        for (int off = 1; off < 64; off <<= 1) ls += __shfl_xor(ls, off);
        if ((t & 63) == 0) redl[w][u] = ls;
    }
    __syncthreads();

    // PV partial: thread (w, d); wave w covers local rows w*64..+63, 4 at a time
    int d = t & 63;
    const float* vb = v + ((size_t)b * L * H + h) * D + d;
    float acc[U];
    #pragma unroll
    for (int u = 0; u < U; ++u) acc[u] = 0.f;
    int rbase = (rch << 8) + (w << 6);
    for (int rr = 0; rr < 64; rr += 4) {
        float v0 = vb[(size_t)(rbase + rr    ) * (H * D)];
        float v1 = vb[(size_t)(rbase + rr + 1) * (H * D)];
        float v2 = vb[(size_t)(rbase + rr + 2) * (H * D)];
        float v3 = vb[(size_t)(rbase + rr + 3) * (H * D)];
        int rl = (w << 6) + rr;
        #pragma unroll
        for (int u = 0; u < U; ++u) {
            float4 p4 = *reinterpret_cast<const float4*>(&pe[u][rl]);
            acc[u] = fmaf(p4.x, v0, fmaf(p4.y, v1, fmaf(p4.z, v2, fmaf(p4.w, v3, acc[u]))));
        }
    }

    // per-wave partial chunk c = rch*4 + w; coalesced 256B stores per u
    size_t pb0 = (size_t)bh * U;
    int c = (rch << 2) + w;
    #pragma unroll
    for (int u = 0; u < U; ++u) {
        pacc[((pb0 + u) * NCHK + c) * 64 + d] = acc[u];
    }
    if (t < U) {
        float pmv = fmaxf(fmaxf(redm[0][t], redm[1][t]), fmaxf(redm[2][t], redm[3][t]));
        float plv = redl[0][t] + redl[1][t] + redl[2][t] + redl[3][t];
        pm[(pb0 + t) * RCH + rch] = pmv;
        pl[(pb0 + t) * RCH + rch] = plv;
    }
}

// ---------------------------------------------------------------------------
// Kernel 4: online-softmax merge of the partials + scatter into out.
// Thread per (bh,u,d). Grid = B*H*U*64/256 = 640 blocks.
// ---------------------------------------------------------------------------
__global__ __launch_bounds__(256) void flash_merge_kernel(
        const float* __restrict__ pm, const float* __restrict__ pl,
        const float* __restrict__ pacc, const int* __restrict__ Mtop,
        float* __restrict__ out) {
    int idx = blockIdx.x * 256 + threadIdx.x;   // 0 .. B*H*U*64-1
    int dd = idx & 63;
    int bhu = idx >> 6;                          // 0..2559
    int bh = bhu / U;
    int b = bh / H, h = bh % H;

    float m = -FLT_MAX;
    #pragma unroll
    for (int c = 0; c < RCH; ++c) m = fmaxf(m, pm[bhu * RCH + c]);

    float Lsum = 0.f, acc = 0.f;
    #pragma unroll
    for (int c = 0; c < RCH; ++c) {
        float wgt = __expf(pm[bhu * RCH + c] - m);
        Lsum += pl[bhu * RCH + c] * wgt;
        float sub = 0.f;
        #pragma unroll
        for (int wv = 0; wv < 4; ++wv)
            sub += pacc[((size_t)bhu * NCHK + (c * 4 + wv)) * 64 + dd];
        acc += sub * wgt;
    }

    int qi = Mtop[bhu];
    out[((size_t)(b * L + qi) * H + h) * D + dd] = acc / Lsum;
}

// ---------------------------------------------------------------------------
// Fallback attention if workspace too small for the flash partials.
// ---------------------------------------------------------------------------
__global__ __launch_bounds__(256) void attn_kernel_fallback(
        const float* __restrict__ q, const float* __restrict__ k,
        const float* __restrict__ v, const int* __restrict__ Mtop,
        float* __restrict__ out) {
    int blk = blockIdx.x;
    int bh = blk / U;
    int u = blk % U;
    int b = bh / H;
    int h = bh % H;
    int qi = Mtop[bh * U + u];

    __shared__ float sc[L];
    __shared__ float qsf[D];
    __shared__ float red[4];
    __shared__ float ctx_s[4][D];

    int t = threadIdx.x;
    if (t < D) qsf[t] = q[((size_t)(b * L + qi)) * H * D + h * D + t];
    __syncthreads();

    float lm = -FLT_MAX;
    for (int i = t; i < L; i += 256) {
        const float* krow = k + ((size_t)(b * L + i)) * H * D + h * D;
        float acc = 0.f;
        #pragma unroll
        for (int dd = 0; dd < D; ++dd) acc += qsf[dd] * krow[dd];
        acc *= 0.125f;
        sc[i] = acc;
        lm = fmaxf(lm, acc);
    }
    #pragma unroll
    for (int off = 32; off >= 1; off >>= 1) lm = fmaxf(lm, __shfl_xor(lm, off));
    if ((t & 63) == 0) red[t >> 6] = lm;
    __syncthreads();
    float gm = fmaxf(fmaxf(red[0], red[1]), fmaxf(red[2], red[3]));

    float ls = 0.f;
    for (int i = t; i < L; i += 256) {
        float e = expf(sc[i] - gm);
        sc[i] = e;
        ls += e;
    }
    #pragma unroll
    for (int off = 32; off >= 1; off >>= 1) ls += __shfl_xor(ls, off);
    __syncthreads();
    if ((t & 63) == 0) red[t >> 6] = ls;
    __syncthreads();
    float inv = 1.0f / (red[0] + red[1] + red[2] + red[3]);

    int d = t & 63;
    int g = t >> 6;
    float acc = 0.f;
    for (int i = g; i < L; i += 4) {
        acc += sc[i] * v[((size_t)(b * L + i)) * H * D + h * D + d];
    }
    ctx_s[g][d] = acc;
    __syncthreads();
    if (g == 0) {
        float c = (ctx_s[0][d] + ctx_s[1][d] + ctx_s[2][d] + ctx_s[3][d]) * inv;
        out[((size_t)(b * L + qi)) * H * D + h * D + d] = c;
    }
}

// ---------------------------------------------------------------------------
extern "C" void kernel_launch(void* const* d_in, const int* in_sizes, int n_in,
                              void* d_out, int out_size, void* d_ws, size_t ws_size,
                              hipStream_t stream) {
    const float* q = (const float*)d_in[0];
    const float* k = (const float*)d_in[1];
    const float* v = (const float*)d_in[2];
    const int* sidx = (const int*)d_in[3];
    float* out = (float*)d_out;

    int SK = in_sizes[3] / L;  // sample_k (40 for this shape)

    // Workspace layout
    size_t offM = 0;                                            // B*H*L floats
    size_t offMtop = offM + (size_t)B * H * L * sizeof(float);
    size_t offPm = (offMtop + (size_t)B * H * U * sizeof(int) + 255) & ~(size_t)255;
    size_t offPl = offPm + (size_t)B * H * U * RCH * sizeof(float);
    size_t offPacc = (offPl + (size_t)B * H * U * RCH * sizeof(float) + 255) & ~(size_t)255;
    size_t needFlash = offPacc + (size_t)B * H * U * NCHK * 64 * sizeof(float);

    float* M = (float*)((char*)d_ws + offM);
    int* Mtop = (int*)((char*)d_ws + offMtop);
    float* pm = (float*)((char*)d_ws + offPm);
    float* pl = (float*)((char*)d_ws + offPl);
    float* pacc = (float*)((char*)d_ws + offPacc);

    int n4 = (B * L * H * D) / 4;

    copy_v_kernel<<<2048, 256, 0, stream>>>(v, out, n4);

    if (SK == 40) {
        compute_M_kernel2<40><<<B * H * (L / LPB), 256, 0, stream>>>(q, k, sidx, M);
    } else {
        compute_M_kernel<<<B * L, 256, 0, stream>>>(q, k, sidx, M, SK);
    }
    topk_wave_kernel<<<B * H, 64, 0, stream>>>(M, Mtop);

    if (ws_size >= needFlash) {
        flash_kernel<<<B * H * RCH, 256, 0, stream>>>(q, k, v, Mtop, pm, pl, pacc);
        flash_merge_kernel<<<B * H * U * 64 / 256, 256, 0, stream>>>(pm, pl, pacc, Mtop, out);
    } else {
        attn_kernel_fallback<<<B * H * U, 256, 0, stream>>>(q, k, v, Mtop, out);
    }
}

// Round 12
// 210.337 us; speedup vs baseline: 3.1719x; 1.0917x over previous
//
#include <hip/hip_runtime.h>
#include <hip/hip_bf16.h>
#include <float.h>
#include <math.h>

// Problem constants (B, L, H, D fixed by the reference setup)
constexpr int B = 4;
constexpr int L = 2048;
constexpr int H = 16;
constexpr int D = 64;
constexpr int U = 40;   // u_top = min(5*ceil(ln(2048)), 2048) = 40
constexpr int UH = 20;  // u's per thread-half in flash
constexpr int RCH = 8;  // key chunks of 256 rows (split-K blocks)
constexpr int NCHK = RCH * 4;  // 32 partial chunks (per-wave-group)
constexpr int LPB = 16; // l's per block in compute_M

typedef float floatx4 __attribute__((ext_vector_type(4)));

// ---------------------------------------------------------------------------
// Kernel 0: out = v  (identity copy), nontemporal both ways.
// ---------------------------------------------------------------------------
__global__ __launch_bounds__(256) void copy_v_kernel(const float* __restrict__ v,
                                                     float* __restrict__ out, int n4) {
    int i = blockIdx.x * blockDim.x + threadIdx.x;
    int stride = gridDim.x * blockDim.x;
    const floatx4* src = reinterpret_cast<const floatx4*>(v);
    floatx4* dst = reinterpret_cast<floatx4*>(out);
    for (; i < n4; i += stride) {
        floatx4 x = __builtin_nontemporal_load(src + i);
        __builtin_nontemporal_store(x, dst + i);
    }
}

// ---------------------------------------------------------------------------
// Kernel 1 (round-4 proven, 83us): M[b,h,l], 16 l's per block, XCD-affinity
// by bh so each XCD's L2 holds 8 bh k-slices. 16-lane group per l.
// ---------------------------------------------------------------------------
template<int SKC>
__global__ __launch_bounds__(256) void compute_M_kernel2(const float* __restrict__ q,
                                                         const float* __restrict__ k,
                                                         const int* __restrict__ sidx,
                                                         float* __restrict__ M) {
    int blk = blockIdx.x;
    int xcd = blk & 7;
    int rest = blk >> 3;
    int bh_hi = rest & 7;
    int chunk = rest >> 3;            // 0 .. L/LPB-1
    int bh = bh_hi * 8 + xcd;         // bh%8 == blk%8
    int b = bh >> 4, h = bh & 15;

    int t = threadIdx.x;
    int lg = t >> 4;                  // local l 0..15
    int dg = t & 15;                  // 4-float group of D

    __shared__ int s_idx[LPB * SKC];
    for (int i = t; i < LPB * SKC; i += 256)
        s_idx[i] = sidx[(size_t)(chunk * LPB) * SKC + i];
    __syncthreads();

    int l = chunk * LPB + lg;
    floatx4 qv = __builtin_nontemporal_load(
        reinterpret_cast<const floatx4*>(q + ((size_t)(b * L + l) * H + h) * D + dg * 4));

    float mx = -FLT_MAX;
    float sm = 0.f;
    #pragma unroll 4
    for (int s = 0; s < SKC; ++s) {
        int kidx = s_idx[lg * SKC + s];
        floatx4 kv = *reinterpret_cast<const floatx4*>(
            k + ((size_t)(b * L + kidx) * H + h) * D + dg * 4);
        float p = qv.x * kv.x + qv.y * kv.y + qv.z * kv.z + qv.w * kv.w;
        #pragma unroll
        for (int off = 8; off >= 1; off >>= 1) p += __shfl_xor(p, off, 16);
        mx = fmaxf(mx, p);
        sm += p;
    }
    if (dg == 0) {
        M[(size_t)bh * L + l] = mx - sm * (1.0f / (float)L);
    }
}

// Fallback M for unexpected SK
__global__ __launch_bounds__(256) void compute_M_kernel(const float* __restrict__ q,
                                                        const float* __restrict__ k,
                                                        const int* __restrict__ sidx,
                                                        float* __restrict__ M, int SK) {
    int bl = blockIdx.x;
    int b = bl / L;
    int l = bl % L;
    int t = threadIdx.x;
    int h = t >> 4;
    int dg = t & 15;

    const float* qrow = q + ((size_t)(b * L + l)) * H * D + h * D + dg * 4;
    float4 qv = *reinterpret_cast<const float4*>(qrow);

    float mx = -FLT_MAX;
    float sm = 0.f;
    for (int s = 0; s < SK; ++s) {
        int kidx = sidx[l * SK + s];
        const float* krow = k + ((size_t)(b * L + kidx)) * H * D + h * D + dg * 4;
        float4 kv = *reinterpret_cast<const float4*>(krow);
        float p = qv.x * kv.x + qv.y * kv.y + qv.z * kv.z + qv.w * kv.w;
        #pragma unroll
        for (int off = 8; off >= 1; off >>= 1) p += __shfl_xor(p, off, 16);
        mx = fmaxf(mx, p);
        sm += p;
    }
    if (dg == 0) {
        M[((size_t)(b * H + h)) * L + l] = mx - sm * (1.0f / (float)L);
    }
}

// ---------------------------------------------------------------------------
// Kernel 2: one wave per (b,h), register-resident top-U, jax.lax.top_k
// tie-breaking (equal value -> lower index wins).
// ---------------------------------------------------------------------------
__global__ __launch_bounds__(64) void topk_wave_kernel(const float* __restrict__ M,
                                                       int* __restrict__ Mtop) {
    int bh = blockIdx.x;
    int lane = threadIdx.x;  // 0..63
    const float* m = M + (size_t)bh * L;

    float v[32];
    #pragma unroll
    for (int j = 0; j < 32; ++j) v[j] = m[j * 64 + lane];

    for (int u = 0; u < U; ++u) {
        float bv = -FLT_MAX;
        int bi = 0x7fffffff;
        #pragma unroll
        for (int j = 0; j < 32; ++j) {
            int idx = j * 64 + lane;
            bool take = (v[j] > bv) || (v[j] == bv && idx < bi);
            bv = take ? v[j] : bv;
            bi = take ? idx : bi;
        }
        #pragma unroll
        for (int off = 1; off < 64; off <<= 1) {
            float ov = __shfl_xor(bv, off);
            int   oi = __shfl_xor(bi, off);
            bool take = (ov > bv) || (ov == bv && oi < bi);
            bv = take ? ov : bv;
            bi = take ? oi : bi;
        }
        if (lane == 0) Mtop[bh * U + u] = bi;
        #pragma unroll
        for (int j = 0; j < 32; ++j) {
            if (bi == j * 64 + lane) v[j] = -FLT_MAX;
        }
    }
}

// ---------------------------------------------------------------------------
// Kernel 3: fused split-K flash attention, 512 threads/block, u split across
// thread halves: t<256 -> u in [0,20), t>=256 -> u in [20,40), same 256-key
// chunk. Register state is s[20]/acc[20] (round 11's s[40]/acc[40] drove
// VGPR to ~256 -> 1 block/CU -> latency-bound). k/v still read once per
// (bh,chunk); both halves share k-row addresses (L1 broadcast). Arithmetic
// is bit-identical to round 11.
// ---------------------------------------------------------------------------
__global__ __launch_bounds__(512) void flash_kernel(
        const float* __restrict__ q, const float* __restrict__ k,
        const float* __restrict__ v, const int* __restrict__ Mtop,
        float* __restrict__ pm, float* __restrict__ pl, float* __restrict__ pacc) {
    int blk = blockIdx.x;           // 0..511
    int xcd = blk & 7;
    int bh = ((blk >> 3) & 7) * 8 + xcd;   // bh%8 == blk%8 (XCD affinity)
    int rch = blk >> 6;             // 0..7
    int b = bh >> 4, h = bh & 15;
    int t = threadIdx.x;            // 0..511
    int tt = t & 255;               // key-row owner within half
    int uh = t >> 8;                // u-half 0/1
    int u0 = uh * UH;
    int w = t >> 6;                 // global wave 0..7 (0-3 = half 0, 4-7 = half 1)

    __shared__ __align__(16) float qs[U][D];    // 10 KB
    __shared__ __align__(16) float pe[U][256];  // 40 KB
    __shared__ float redm[8][U];                // 1.25 KB
    __shared__ float redl[8][U];                // 1.25 KB

    // stage 40 q rows (broadcast source)
    for (int i = t; i < U * D; i += 512) {
        int u = i >> 6, dd = i & 63;
        int qi = Mtop[bh * U + u];
        qs[u][dd] = q[((size_t)(b * L + qi) * H + h) * D + dd];
    }
    __syncthreads();

    // scores: thread owns key row r for its 20 u's; j-outer streaming
    int r = (rch << 8) + tt;
    const float4* krow = reinterpret_cast<const float4*>(k + ((size_t)(b * L + r) * H + h) * D);

    float s[UH];
    #pragma unroll
    for (int uu = 0; uu < UH; ++uu) s[uu] = 0.f;
    #pragma unroll 4
    for (int j = 0; j < 16; ++j) {
        float4 kj = krow[j];
        #pragma unroll
        for (int uu = 0; uu < UH; ++uu) {
            float4 qj = reinterpret_cast<const float4*>(qs[u0 + uu])[j];
            s[uu] = fmaf(kj.x, qj.x, fmaf(kj.y, qj.y, fmaf(kj.z, qj.z, fmaf(kj.w, qj.w, s[uu]))));
        }
    }

    // block max per u (shfl across wave, then LDS across the half's 4 waves)
    #pragma unroll
    for (int uu = 0; uu < UH; ++uu) {
        float m = s[uu] * 0.125f;    // 1/sqrt(64)
        s[uu] = m;
        #pragma unroll
        for (int off = 1; off < 64; off <<= 1) m = fmaxf(m, __shfl_xor(m, off));
        if ((t & 63) == 0) redm[w][u0 + uu] = m;
    }
    __syncthreads();

    // exp + block sum per u; stash e in LDS
    int wb = uh * 4;   // first wave of this half
    #pragma unroll
    for (int uu = 0; uu < UH; ++uu) {
        int u = u0 + uu;
        float m_u = fmaxf(fmaxf(redm[wb][u], redm[wb + 1][u]),
                          fmaxf(redm[wb + 2][u], redm[wb + 3][u]));
        float e = __expf(s[uu] - m_u);
        pe[u][tt] = e;
        float ls = e;
        #pragma unroll
        for (int off = 1; off < 64; off <<= 1) ls += __shfl_xor(ls, off);
        if ((t & 63) == 0) redl[w][u] = ls;
    }
    __syncthreads();

    // PV partial: wave w_local of each half covers local rows w_local*64..+63
    int d = t & 63;
    int w_local = (t >> 6) & 3;
    const float* vb = v + ((size_t)b * L * H + h) * D + d;
    float acc[UH];
    #pragma unroll
    for (int uu = 0; uu < UH; ++uu) acc[uu] = 0.f;
    int rbase = (rch << 8) + (w_local << 6);
    #pragma unroll 2
    for (int rr = 0; rr < 64; rr += 4) {
        float v0 = vb[(size_t)(rbase + rr    ) * (H * D)];
        float v1 = vb[(size_t)(rbase + rr + 1) * (H * D)];
        float v2 = vb[(size_t)(rbase + rr + 2) * (H * D)];
        float v3 = vb[(size_t)(rbase + rr + 3) * (H * D)];
        int rl = (w_local << 6) + rr;
        #pragma unroll
        for (int uu = 0; uu < UH; ++uu) {
            float4 p4 = *reinterpret_cast<const float4*>(&pe[u0 + uu][rl]);
            acc[uu] = fmaf(p4.x, v0, fmaf(p4.y, v1, fmaf(p4.z, v2, fmaf(p4.w, v3, acc[uu]))));
        }
    }

    // per-wave partial chunk c = rch*4 + w_local; coalesced 256B stores per u
    size_t pb0 = (size_t)bh * U;
    int c = (rch << 2) + w_local;
    #pragma unroll
    for (int uu = 0; uu < UH; ++uu) {
        pacc[((pb0 + u0 + uu) * NCHK + c) * 64 + d] = acc[uu];
    }
    if (t < U) {
        int base = (t < UH) ? 0 : 4;
        float pmv = fmaxf(fmaxf(redm[base][t], redm[base + 1][t]),
                          fmaxf(redm[base + 2][t], redm[base + 3][t]));
        float plv = redl[base][t] + redl[base + 1][t] + redl[base + 2][t] + redl[base + 3][t];
        pm[(pb0 + t) * RCH + rch] = pmv;
        pl[(pb0 + t) * RCH + rch] = plv;
    }
}

// ---------------------------------------------------------------------------
// Kernel 4: online-softmax merge of the partials + scatter into out.
// Thread per (bh,u,d). Grid = B*H*U*64/256 = 640 blocks.
// ---------------------------------------------------------------------------
__global__ __launch_bounds__(256) void flash_merge_kernel(
        const float* __restrict__ pm, const float* __restrict__ pl,
        const float* __restrict__ pacc, const int* __restrict__ Mtop,
        float* __restrict__ out) {
    int idx = blockIdx.x * 256 + threadIdx.x;   // 0 .. B*H*U*64-1
    int dd = idx & 63;
    int bhu = idx >> 6;                          // 0..2559
    int bh = bhu / U;
    int b = bh / H, h = bh % H;

    float m = -FLT_MAX;
    #pragma unroll
    for (int c = 0; c < RCH; ++c) m = fmaxf(m, pm[bhu * RCH + c]);

    float Lsum = 0.f, acc = 0.f;
    #pragma unroll
    for (int c = 0; c < RCH; ++c) {
        float wgt = __expf(pm[bhu * RCH + c] - m);
        Lsum += pl[bhu * RCH + c] * wgt;
        float sub = 0.f;
        #pragma unroll
        for (int wv = 0; wv < 4; ++wv)
            sub += pacc[((size_t)bhu * NCHK + (c * 4 + wv)) * 64 + dd];
        acc += sub * wgt;
    }

    int qi = Mtop[bhu];
    out[((size_t)(b * L + qi) * H + h) * D + dd] = acc / Lsum;
}

// ---------------------------------------------------------------------------
// Fallback attention if workspace too small for the flash partials.
// ---------------------------------------------------------------------------
__global__ __launch_bounds__(256) void attn_kernel_fallback(
        const float* __restrict__ q, const float* __restrict__ k,
        const float* __restrict__ v, const int* __restrict__ Mtop,
        float* __restrict__ out) {
    int blk = blockIdx.x;
    int bh = blk / U;
    int u = blk % U;
    int b = bh / H;
    int h = bh % H;
    int qi = Mtop[bh * U + u];

    __shared__ float sc[L];
    __shared__ float qsf[D];
    __shared__ float red[4];
    __shared__ float ctx_s[4][D];

    int t = threadIdx.x;
    if (t < D) qsf[t] = q[((size_t)(b * L + qi)) * H * D + h * D + t];
    __syncthreads();

    float lm = -FLT_MAX;
    for (int i = t; i < L; i += 256) {
        const float* krow = k + ((size_t)(b * L + i)) * H * D + h * D;
        float acc = 0.f;
        #pragma unroll
        for (int dd = 0; dd < D; ++dd) acc += qsf[dd] * krow[dd];
        acc *= 0.125f;
        sc[i] = acc;
        lm = fmaxf(lm, acc);
    }
    #pragma unroll
    for (int off = 32; off >= 1; off >>= 1) lm = fmaxf(lm, __shfl_xor(lm, off));
    if ((t & 63) == 0) red[t >> 6] = lm;
    __syncthreads();
    float gm = fmaxf(fmaxf(red[0], red[1]), fmaxf(red[2], red[3]));

    float ls = 0.f;
    for (int i = t; i < L; i += 256) {
        float e = expf(sc[i] - gm);
        sc[i] = e;
        ls += e;
    }
    #pragma unroll
    for (int off = 32; off >= 1; off >>= 1) ls += __shfl_xor(ls, off);
    __syncthreads();
    if ((t & 63) == 0) red[t >> 6] = ls;
    __syncthreads();
    float inv = 1.0f / (red[0] + red[1] + red[2] + red[3]);

    int d = t & 63;
    int g = t >> 6;
    float acc = 0.f;
    for (int i = g; i < L; i += 4) {
        acc += sc[i] * v[((size_t)(b * L + i)) * H * D + h * D + d];
    }
    ctx_s[g][d] = acc;
    __syncthreads();
    if (g == 0) {
        float c = (ctx_s[0][d] + ctx_s[1][d] + ctx_s[2][d] + ctx_s[3][d]) * inv;
        out[((size_t)(b * L + qi)) * H * D + h * D + d] = c;
    }
}

// ---------------------------------------------------------------------------
extern "C" void kernel_launch(void* const* d_in, const int* in_sizes, int n_in,
                              void* d_out, int out_size, void* d_ws, size_t ws_size,
                              hipStream_t stream) {
    const float* q = (const float*)d_in[0];
    const float* k = (const float*)d_in[1];
    const float* v = (const float*)d_in[2];
    const int* sidx = (const int*)d_in[3];
    float* out = (float*)d_out;

    int SK = in_sizes[3] / L;  // sample_k (40 for this shape)

    // Workspace layout
    size_t offM = 0;                                            // B*H*L floats
    size_t offMtop = offM + (size_t)B * H * L * sizeof(float);
    size_t offPm = (offMtop + (size_t)B * H * U * sizeof(int) + 255) & ~(size_t)255;
    size_t offPl = offPm + (size_t)B * H * U * RCH * sizeof(float);
    size_t offPacc = (offPl + (size_t)B * H * U * RCH * sizeof(float) + 255) & ~(size_t)255;
    size_t needFlash = offPacc + (size_t)B * H * U * NCHK * 64 * sizeof(float);

    float* M = (float*)((char*)d_ws + offM);
    int* Mtop = (int*)((char*)d_ws + offMtop);
    float* pm = (float*)((char*)d_ws + offPm);
    float* pl = (float*)((char*)d_ws + offPl);
    float* pacc = (float*)((char*)d_ws + offPacc);

    int n4 = (B * L * H * D) / 4;

    copy_v_kernel<<<2048, 256, 0, stream>>>(v, out, n4);

    if (SK == 40) {
        compute_M_kernel2<40><<<B * H * (L / LPB), 256, 0, stream>>>(q, k, sidx, M);
    } else {
        compute_M_kernel<<<B * L, 256, 0, stream>>>(q, k, sidx, M, SK);
    }
    topk_wave_kernel<<<B * H, 64, 0, stream>>>(M, Mtop);

    if (ws_size >= needFlash) {
        flash_kernel<<<B * H * RCH, 512, 0, stream>>>(q, k, v, Mtop, pm, pl, pacc);
        flash_merge_kernel<<<B * H * U * 64 / 256, 256, 0, stream>>>(pm, pl, pacc, Mtop, out);
    } else {
        attn_kernel_fallback<<<B * H * U, 256, 0, stream>>>(q, k, v, Mtop, out);
    }
}